// Round 1
// baseline (466.816 us; speedup 1.0000x reference)
//
#include <hip/hip_runtime.h>
#include <hip/hip_bf16.h>
#include <stdint.h>

#define NN 4096
#define NF 128
#define NBATCH 4

typedef __attribute__((ext_vector_type(4))) float  floatx4;
typedef __attribute__((ext_vector_type(8))) __bf16 bf16x8;

// ---------------------------------------------------------------------------
// Prep: XT[b][n][k] = bf16(X[b][k][n])  (transposed for contiguous B-frags)
//       wT[n][k]    = bf16(w[k][n])
// ---------------------------------------------------------------------------
__global__ __launch_bounds__(256) void prep_kernel(const float* __restrict__ X,
                                                   const float* __restrict__ w,
                                                   __bf16* __restrict__ XT,
                                                   __bf16* __restrict__ wT) {
    int bx = blockIdx.x;
    if (bx == 1024) {  // tiny: w transpose (128x128)
        for (int i = threadIdx.x; i < NF * NF; i += 256) {
            int n = i >> 7, k = i & 127;
            wT[i] = (__bf16)w[k * NF + n];
        }
        return;
    }
    // 1024 blocks * 256 threads = 262144 = 4 batches * 128 n * 512 k-chunks
    int id  = bx * 256 + threadIdx.x;
    int b   = id >> 16;
    int rem = id & 65535;
    int kc  = rem >> 7;   // k-chunk of 8
    int n   = rem & 127;  // consecutive lanes -> consecutive n: coalesced reads
    const float* Xp = X + (size_t)b * NN * NF + (size_t)kc * 8 * NF + n;
    bf16x8 v;
#pragma unroll
    for (int i = 0; i < 8; i++) v[i] = (__bf16)Xp[(size_t)i * NF];
    *(bf16x8*)(XT + (size_t)b * NF * NN + (size_t)n * NN + kc * 8) = v;
}

// ---------------------------------------------------------------------------
// Main: per block: 64 rows x 128 cols of  relu(((A@X + X)/deg) @ w)
// 4 waves, wave w owns rows [m0+16w, m0+16w+16), all 128 cols (8 acc frags).
// K-loop is barrier-free: A frags straight from global (fp32->bf16 in regs),
// B frags straight from XT (L2-resident, 4MB). deg accumulated during loads.
// ---------------------------------------------------------------------------
__global__ __launch_bounds__(256, 1) void main_kernel(const float* __restrict__ A,
                                                      const float* __restrict__ X,
                                                      const __bf16* __restrict__ XT,
                                                      const __bf16* __restrict__ wT,
                                                      float* __restrict__ out) {
    __shared__ __bf16 Us[64][136];    // u = (acc+X)/deg, bf16, padded rows
    __shared__ __bf16 wTs[128][136];  // w^T staged, padded rows
    __shared__ float  degs[64];

    const int tid  = threadIdx.x;
    const int wv   = tid >> 6;
    const int lane = tid & 63;
    const int lm   = lane & 15;   // m-index in A-frag / n-index in B-frag
    const int quad = lane >> 4;   // k-group

    const int bx = blockIdx.x;         // 256 blocks = 4 batches * 64 m-blocks
    const int b  = bx >> 6;
    const int m0 = (bx & 63) * 64;

    // stage wT -> LDS (read after first barrier)
    for (int i = tid; i < NF * NF; i += 256)
        wTs[i >> 7][i & 127] = wT[i];

    const int row = m0 + wv * 16 + lm;
    const float*  Arow = A  + ((size_t)b * NN + row) * NN + quad * 8;
    const __bf16* XTb  = XT + (size_t)b * NF * NN + (size_t)lm * NN + quad * 8;

    floatx4 acc[8];
#pragma unroll
    for (int t = 0; t < 8; t++) acc[t] = (floatx4){0.f, 0.f, 0.f, 0.f};
    float dsum = 0.f;

    // prologue loads (register double-buffer)
    floatx4 a0 = *(const floatx4*)(Arow);
    floatx4 a1 = *(const floatx4*)(Arow + 4);
    bf16x8 bfr[8];
#pragma unroll
    for (int nt = 0; nt < 8; nt++)
        bfr[nt] = *(const bf16x8*)(XTb + (size_t)nt * 16 * NN);

#pragma unroll 2
    for (int k0 = 0; k0 < NN; k0 += 32) {
        floatx4 na0, na1;
        bf16x8  nb[8];
        if (k0 + 32 < NN) {  // prefetch next iter
            const float* Ap = Arow + k0 + 32;
            na0 = *(const floatx4*)(Ap);
            na1 = *(const floatx4*)(Ap + 4);
            const __bf16* Bp = XTb + k0 + 32;
#pragma unroll
            for (int nt = 0; nt < 8; nt++)
                nb[nt] = *(const bf16x8*)(Bp + (size_t)nt * 16 * NN);
        }
        // exact fp32 row-sum for deg (lanes with same lm cover disjoint k)
        dsum += a0[0] + a0[1] + a0[2] + a0[3] + a1[0] + a1[1] + a1[2] + a1[3];
        bf16x8 af;
#pragma unroll
        for (int i = 0; i < 4; i++) af[i] = (__bf16)a0[i];
#pragma unroll
        for (int i = 0; i < 4; i++) af[4 + i] = (__bf16)a1[i];
#pragma unroll
        for (int nt = 0; nt < 8; nt++)
            acc[nt] = __builtin_amdgcn_mfma_f32_16x16x32_bf16(af, bfr[nt], acc[nt], 0, 0, 0);
        a0 = na0; a1 = na1;
#pragma unroll
        for (int nt = 0; nt < 8; nt++) bfr[nt] = nb[nt];
    }

    // deg[row]: reduce the 4 k-phases (lanes lm, lm+16, lm+32, lm+48)
    dsum += __shfl_xor(dsum, 16, 64);
    dsum += __shfl_xor(dsum, 32, 64);
    if (lane < 16) degs[wv * 16 + lm] = dsum + 1.0f;
    __syncthreads();

    // u = (acc + X) / deg  -> Us (bf16, A-operand layout for epilogue GEMM)
    const float* Xb = X + ((size_t)b * NN + m0) * NF;
#pragma unroll
    for (int nt = 0; nt < 8; nt++) {
        int col = nt * 16 + lm;
#pragma unroll
        for (int i = 0; i < 4; i++) {
            int r = wv * 16 + quad * 4 + i;  // C-layout: row=(lane>>4)*4+reg
            float u = (acc[nt][i] + Xb[(size_t)r * NF + col]) / degs[r];
            Us[r][col] = (__bf16)u;
        }
    }
    __syncthreads();

    // z = u @ w  (K=128, 4 MFMA k-steps x 8 n-tiles per wave)
    floatx4 z[8];
#pragma unroll
    for (int t = 0; t < 8; t++) z[t] = (floatx4){0.f, 0.f, 0.f, 0.f};
#pragma unroll
    for (int kk = 0; kk < NF; kk += 32) {
        bf16x8 ua = *(const bf16x8*)&Us[wv * 16 + lm][kk + quad * 8];
#pragma unroll
        for (int nt = 0; nt < 8; nt++) {
            bf16x8 wb = *(const bf16x8*)&wTs[nt * 16 + lm][kk + quad * 8];
            z[nt] = __builtin_amdgcn_mfma_f32_16x16x32_bf16(ua, wb, z[nt], 0, 0, 0);
        }
    }

    // relu + store
    float* ob = out + ((size_t)b * NN + m0) * NF;
#pragma unroll
    for (int nt = 0; nt < 8; nt++) {
        int col = nt * 16 + lm;
#pragma unroll
        for (int i = 0; i < 4; i++) {
            int r = wv * 16 + quad * 4 + i;
            float v = z[nt][i];
            ob[(size_t)r * NF + col] = v > 0.f ? v : 0.f;
        }
    }
}

extern "C" void kernel_launch(void* const* d_in, const int* in_sizes, int n_in,
                              void* d_out, int out_size, void* d_ws, size_t ws_size,
                              hipStream_t stream) {
    const float* A = (const float*)d_in[0];  // [4,4096,4096]
    const float* X = (const float*)d_in[1];  // [4,4096,128]
    const float* w = (const float*)d_in[2];  // [128,128]
    float* out = (float*)d_out;              // [4,4096,128]

    __bf16* XT = (__bf16*)d_ws;                         // 4 MB
    __bf16* wT = XT + (size_t)NBATCH * NF * NN;         // +32 KB

    prep_kernel<<<1025, 256, 0, stream>>>(X, w, XT, wT);
    main_kernel<<<256, 256, 0, stream>>>(A, X, XT, wT, out);
}